// Round 4
// baseline (203.083 us; speedup 1.0000x reference)
//
#include <hip/hip_runtime.h>
#include <hip/hip_bf16.h>
#include <stdint.h>

typedef __attribute__((ext_vector_type(4))) float f32x4;
typedef __attribute__((ext_vector_type(8))) short short8;

#define NN 4096      // nodes
#define FIN 128
#define FHID 64
#define BATCH 32
#define NJ 2048      // BATCH * FHID

// ---------- helpers ----------
__device__ __forceinline__ unsigned short f2bf(float f) {
  unsigned u = __builtin_bit_cast(unsigned, f);
  u = (u + 0x7FFFu + ((u >> 16) & 1u)) >> 16;   // RNE
  return (unsigned short)u;
}
__device__ __forceinline__ float bf2f(unsigned short h) {
  unsigned u = ((unsigned)h) << 16;
  return __builtin_bit_cast(float, u);
}
__device__ __forceinline__ void gload_lds16(const void* g, void* l) {
  __builtin_amdgcn_global_load_lds(
      (const __attribute__((address_space(1))) unsigned int*)g,
      (__attribute__((address_space(3))) unsigned int*)l, 16, 0, 0);
}

// ---------- K0: adj fp32 -> bf16 ----------
__global__ __launch_bounds__(256) void k_convert(const float* __restrict__ adj,
                                                 unsigned short* __restrict__ adjb) {
  long i = (long)blockIdx.x * 256 + threadIdx.x;   // one float4 per thread
  const f32x4* in = (const f32x4*)adj;
  f32x4 v = in[i];
  ushort4 o;
  o.x = f2bf(v.x); o.y = f2bf(v.y); o.z = f2bf(v.z); o.w = f2bf(v.w);
  *(ushort4*)(adjb + i * 4) = o;
}

// ---------- K1: St[b*64+h][m] = sum_f x[b][m][f] * W1[f][h]  (bf16 out) ----------
// LDS-transposed coalesced stores (16B) replacing 64 strided 2B stores.
__global__ __launch_bounds__(256) void k_support(const float* __restrict__ x,
                                                 const float* __restrict__ W1,
                                                 unsigned short* __restrict__ St) {
  __shared__ float W1s[FIN * FHID];                 // 32 KB
  __shared__ __align__(16) unsigned short T[FHID * 256];  // 32 KB transpose buf
  int tid = threadIdx.x;
  for (int i = tid; i < FIN * FHID; i += 256) W1s[i] = W1[i];
  __syncthreads();

  long r = (long)blockIdx.x * 256 + tid;     // row id: b*4096 + m
  int b  = blockIdx.x >> 4;
  int m0 = (blockIdx.x & 15) * 256;
  const f32x4* xr = (const f32x4*)(x + r * FIN);

  f32x4 acc[16];
  f32x4 z = {0.f, 0.f, 0.f, 0.f};
  #pragma unroll
  for (int i = 0; i < 16; ++i) acc[i] = z;

  #pragma unroll 8
  for (int f4 = 0; f4 < FIN / 4; ++f4) {
    f32x4 xv = xr[f4];
    const f32x4* wrow = (const f32x4*)(W1s + (f4 * 4) * FHID);
    #pragma unroll
    for (int k = 0; k < 4; ++k) {
      float xf = xv[k];
      #pragma unroll
      for (int hq = 0; hq < 16; ++hq) acc[hq] += xf * wrow[k * 16 + hq];
    }
  }
  // transpose via LDS: T[h][m_local]
  #pragma unroll
  for (int hq = 0; hq < 16; ++hq)
    #pragma unroll
    for (int k = 0; k < 4; ++k)
      T[(hq * 4 + k) * 256 + tid] = f2bf(acc[hq][k]);
  __syncthreads();
  // coalesced 16B stores: 64 h-rows x 32 chunks of 8 ushorts
  const short8* Tv = (const short8*)T;
  for (int i = tid; i < FHID * 32; i += 256) {
    int h = i >> 5, c = i & 31;
    *(short8*)(St + (size_t)(b * FHID + h) * NN + m0 + c * 8) = Tv[i];
  }
}

// ---------- K2: H = relu(adjb @ St^T + b1) ----------
// BM=256 x BN=128, BK=64, 8 waves (4M x 2N), per-wave 64x64 (4x4 frags).
// 4-phase schedule per K-tile with half-tile staging, derived counted vmcnt,
// staggered quadrant order (template S per wave), setprio around MFMA,
// XOR-swizzle (byte ^= (row&7)<<4) via pre-swizzled global source.
#define LGKM0 do { asm volatile("s_waitcnt lgkmcnt(0)" ::: "memory"); \
                   __builtin_amdgcn_sched_barrier(0); } while (0)
#define VMW(N) asm volatile("s_waitcnt vmcnt(" #N ")" ::: "memory")

template <int S>
__device__ __forceinline__ void gemm_core(const unsigned short* __restrict__ A,
                                          const unsigned short* __restrict__ Bt,
                                          unsigned short* As, unsigned short* Bs,
                                          int bm, int bn, int tid,
                                          f32x4 (&acc)[4][4]) {
  const int lane = tid & 63;
  const int wv   = tid >> 6;
  const int wm   = wv >> 1;          // 0..3 (M)
  const int wn   = wv & 1;           // 0..1 (N)
  const int fr   = lane & 15;
  const int fq   = lane >> 4;

  // fragment LDS ushort offsets (within current buffer)
  int offA[4][2], offB[4][2];
  #pragma unroll
  for (int mi = 0; mi < 4; ++mi) {
    int row = wm * 32 + (mi & 1) * 16 + (mi >> 1) * 128 + fr;
    #pragma unroll
    for (int ks = 0; ks < 2; ++ks)
      offA[mi][ks] = row * 64 + (((( ks << 6) + (fq << 4)) ^ ((row & 7) << 4)) >> 1);
  }
  #pragma unroll
  for (int ni = 0; ni < 4; ++ni) {
    int row = wn * 32 + (ni & 1) * 16 + (ni >> 1) * 64 + fr;
    #pragma unroll
    for (int ks = 0; ks < 2; ++ks)
      offB[ni][ks] = row * 64 + ((((ks << 6) + (fq << 4)) ^ ((row & 7) << 4)) >> 1);
  }

  // staging addresses (pre-swizzled global source, linear LDS dest)
  const int srow = tid >> 3;
  const int scol = ((((tid & 7) << 4) ^ ((srow & 7) << 4)) >> 1);
  const unsigned short* gA00 = A + (size_t)(bm +   0 +  0 + srow) * NN + scol;
  const unsigned short* gA01 = A + (size_t)(bm +   0 + 64 + srow) * NN + scol;
  const unsigned short* gA10 = A + (size_t)(bm + 128 +  0 + srow) * NN + scol;
  const unsigned short* gA11 = A + (size_t)(bm + 128 + 64 + srow) * NN + scol;
  const unsigned short* gB0  = Bt + (size_t)(bn +  0 + srow) * NN + scol;
  const unsigned short* gB1  = Bt + (size_t)(bn + 64 + srow) * NN + scol;
  const int ld = tid * 8;   // ushort offset of this thread's 16B slot

  short8 av[4][2], bv[4][2];

#define RD_APAIR(P, Ab)                                                        \
  _Pragma("unroll") for (int m2 = 0; m2 < 2; ++m2)                             \
  _Pragma("unroll") for (int ks = 0; ks < 2; ++ks)                             \
    av[2*(P)+m2][ks] = *(const short8*)((Ab) + offA[2*(P)+m2][ks]);
#define RD_BPAIR(P, Bb)                                                        \
  _Pragma("unroll") for (int n2 = 0; n2 < 2; ++n2)                             \
  _Pragma("unroll") for (int ks = 0; ks < 2; ++ks)                             \
    bv[2*(P)+n2][ks] = *(const short8*)((Bb) + offB[2*(P)+n2][ks]);
#define CLUSTER(QM, QN)                                                        \
  __builtin_amdgcn_s_setprio(1);                                               \
  _Pragma("unroll") for (int m2 = 0; m2 < 2; ++m2)                             \
  _Pragma("unroll") for (int n2 = 0; n2 < 2; ++n2)                             \
  _Pragma("unroll") for (int ks = 0; ks < 2; ++ks)                             \
    acc[2*(QM)+m2][2*(QN)+n2] = __builtin_amdgcn_mfma_f32_16x16x32_bf16(       \
        av[2*(QM)+m2][ks], bv[2*(QN)+n2][ks], acc[2*(QM)+m2][2*(QN)+n2], 0,0,0); \
  __builtin_amdgcn_s_setprio(0);

  // ---- prologue: stage tile 0 into buf 0 (order B0,B1,A0,A1) ----
  gload_lds16(gB0,  Bs + 0 * 4096 + ld);
  gload_lds16(gB1,  Bs + 1 * 4096 + ld);
  gload_lds16(gA00, As + 0 * 4096 + ld);
  gload_lds16(gA01, As + 1 * 4096 + ld);
  gload_lds16(gA10, As + 2 * 4096 + ld);
  gload_lds16(gA11, As + 3 * 4096 + ld);
  VMW(2);                                  // B0,B1,A-h0 landed; A-h1 in flight
  __builtin_amdgcn_s_barrier();
  __builtin_amdgcn_sched_barrier(0);

  int kn = 64;    // element k-offset of tile t+1
  #pragma unroll 1
  for (int t = 0; t < 63; ++t) {
    const int cur = t & 1;
    unsigned short* Ac = As + cur * 16384;
    unsigned short* Bc = Bs + cur * 8192;
    unsigned short* An = As + (cur ^ 1) * 16384;
    unsigned short* Bn = Bs + (cur ^ 1) * 8192;
    // P1: stage B-h0(t+1); read A-pair0 + B-first-pair; MFMA Q(0,S)
    gload_lds16(gB0 + kn, Bn + 0 * 4096 + ld);
    RD_APAIR(0, Ac)
    RD_BPAIR(S, Bc)
    LGKM0;
    CLUSTER(0, S)
    // P2: stage B-h1(t+1); read B-second-pair; MFMA Q(0,1-S)
    gload_lds16(gB1 + kn, Bn + 1 * 4096 + ld);
    RD_BPAIR(1 - S, Bc)
    LGKM0;
    CLUSTER(0, 1 - S)
    // mid guard: A-h1(t) must be landed (leave B0,B1(t+1) in flight)
    VMW(2);
    __builtin_amdgcn_s_barrier();
    __builtin_amdgcn_sched_barrier(0);
    // P3: stage A-h0(t+1); read A-pair1; MFMA Q(1,1-S)
    gload_lds16(gA00 + kn, An + 0 * 4096 + ld);
    gload_lds16(gA01 + kn, An + 1 * 4096 + ld);
    RD_APAIR(1, Ac)
    LGKM0;
    CLUSTER(1, 1 - S)
    // P4: stage A-h1(t+1); MFMA Q(1,S)
    gload_lds16(gA10 + kn, An + 2 * 4096 + ld);
    gload_lds16(gA11 + kn, An + 3 * 4096 + ld);
    CLUSTER(1, S)
    // boundary guard: B0,B1,A-h0(t+1) landed (leave A-h1(t+1) in flight)
    VMW(2);
    __builtin_amdgcn_s_barrier();
    __builtin_amdgcn_sched_barrier(0);
    kn += 64;
  }
  // ---- peeled last tile (t=63, cur=1, no staging) ----
  {
    unsigned short* Ac = As + 16384;
    unsigned short* Bc = Bs + 8192;
    RD_APAIR(0, Ac)
    RD_BPAIR(S, Bc)
    LGKM0;
    CLUSTER(0, S)
    RD_BPAIR(1 - S, Bc)
    LGKM0;
    CLUSTER(0, 1 - S)
    VMW(0);                       // drain: A-h1 of last tile
    __builtin_amdgcn_s_barrier();
    __builtin_amdgcn_sched_barrier(0);
    RD_APAIR(1, Ac)
    LGKM0;
    CLUSTER(1, 1 - S)
    CLUSTER(1, S)
  }
#undef RD_APAIR
#undef RD_BPAIR
#undef CLUSTER
}

__global__ __launch_bounds__(512, 1) void k_gemm(const unsigned short* __restrict__ A,
                                                 const unsigned short* __restrict__ Bt,
                                                 const float* __restrict__ b1,
                                                 unsigned short* __restrict__ H) {
  __shared__ __align__(16) unsigned short As[2 * 16384];  // 64 KB (A: 256x64 dbuf)
  __shared__ __align__(16) unsigned short Bs[2 * 8192];   // 32 KB (B: 128x64 dbuf)

  const int tid  = threadIdx.x;
  const int lane = tid & 63;
  const int wv   = tid >> 6;
  const int wm   = wv >> 1;
  const int wn   = wv & 1;
  const int bm   = blockIdx.x * 256;
  const int bn   = blockIdx.y * 128;

  f32x4 z = {0.f, 0.f, 0.f, 0.f};
  f32x4 acc[4][4];
  #pragma unroll
  for (int i = 0; i < 4; ++i)
    #pragma unroll
    for (int j = 0; j < 4; ++j) acc[i][j] = z;

  if ((wm & 1) == 0) gemm_core<0>(A, Bt, As, Bs, bm, bn, tid, acc);
  else               gemm_core<1>(A, Bt, As, Bs, bm, bn, tid, acc);

  // ---- epilogue: bias + relu, store bf16 ----
  const int cr = (lane >> 4) * 4;
  const int cc = lane & 15;
  #pragma unroll
  for (int ni = 0; ni < 4; ++ni) {
    int col = bn + wn * 32 + (ni & 1) * 16 + (ni >> 1) * 64 + cc;
    float bias = b1[col & 63];
    #pragma unroll
    for (int mi = 0; mi < 4; ++mi) {
      int rowb = bm + wm * 32 + (mi & 1) * 16 + (mi >> 1) * 128 + cr;
      #pragma unroll
      for (int r = 0; r < 4; ++r) {
        float v = acc[mi][ni][r] + bias;
        v = v > 0.f ? v : 0.f;
        H[(long)(rowb + r) * NJ + col] = f2bf(v);
      }
    }
  }
}

// ---------- K3: partial[b][c][h] = sum_{n in chunk c} adj[q_b][n] * H[n][b*64+h] ----------
__global__ __launch_bounds__(256) void k_agg(const float* __restrict__ adj,
                                             const int* __restrict__ q_ids,
                                             const unsigned short* __restrict__ H,
                                             float* __restrict__ partial) {
  int b = blockIdx.x;        // 0..31
  int c = blockIdx.y;        // 0..15
  int h = threadIdx.x & 63;
  int w = threadIdx.x >> 6;
  int q = q_ids[b];
  const float* arow = adj + (long)q * NN;
  int j = b * FHID + h;
  float s = 0.f;
  int n0 = c * 256;
  for (int n = n0 + w; n < n0 + 256; n += 4)
    s += arow[n] * bf2f(H[(long)n * NJ + j]);
  __shared__ float red[4][64];
  red[w][h] = s;
  __syncthreads();
  if (w == 0)
    partial[((b << 4) + c) * 64 + h] = red[0][h] + red[1][h] + red[2][h] + red[3][h];
}

// ---------- K4: out[b][l] = sum_h agg[b][h]*W2[h][l] + b2[l] ----------
__global__ __launch_bounds__(1024) void k_out(const float* __restrict__ partial,
                                              const float* __restrict__ W2,
                                              const float* __restrict__ b2,
                                              float* __restrict__ out) {
  __shared__ float aggs[BATCH * FHID];   // 2048
  int t = threadIdx.x;
  for (int idx = t; idx < BATCH * FHID; idx += 1024) {
    int base = (idx >> 6) * (16 * 64) + (idx & 63);
    float s = 0.f;
    #pragma unroll
    for (int c = 0; c < 16; ++c) s += partial[base + c * 64];
    aggs[idx] = s;
  }
  __syncthreads();
  int b = t >> 5, l = t & 31;
  float o = b2[l];
  #pragma unroll
  for (int h = 0; h < FHID; ++h) o += aggs[b * FHID + h] * W2[h * 32 + l];
  out[b * 32 + l] = o;
}

extern "C" void kernel_launch(void* const* d_in, const int* in_sizes, int n_in,
                              void* d_out, int out_size, void* d_ws, size_t ws_size,
                              hipStream_t stream) {
  const float* x   = (const float*)d_in[0];
  const int*   q   = (const int*)d_in[1];
  const float* adj = (const float*)d_in[2];
  const float* W1  = (const float*)d_in[3];
  const float* b1  = (const float*)d_in[4];
  const float* W2  = (const float*)d_in[5];
  const float* b2  = (const float*)d_in[6];
  float* out = (float*)d_out;

  char* ws = (char*)d_ws;
  unsigned short* adjb   = (unsigned short*)ws;                              // 32 MB
  unsigned short* St     = (unsigned short*)(ws + (size_t)32 * 1024 * 1024); // 16 MB
  unsigned short* H      = (unsigned short*)(ws + (size_t)48 * 1024 * 1024); // 16 MB
  float*          partial= (float*)(ws + (size_t)64 * 1024 * 1024);          // 128 KB

  // K0: adj -> bf16
  k_convert<<<(NN * NN / 4) / 256, 256, 0, stream>>>(adj, adjb);
  // K1: support^T
  k_support<<<(BATCH * NN) / 256, 256, 0, stream>>>(x, W1, St);
  // K2: big GEMM + bias + relu (256x128 tiles, 4-phase counted-vmcnt)
  dim3 g2(NN / 256, NJ / 128);
  k_gemm<<<g2, 512, 0, stream>>>(adjb, St, b1, H);
  // K3: row-gather aggregation
  dim3 g3(BATCH, 16);
  k_agg<<<g3, 256, 0, stream>>>(adj, q, H, partial);
  // K4: final tiny GEMM
  k_out<<<1, 1024, 0, stream>>>(partial, W2, b2, out);
}

// Round 5
// 130.861 us; speedup vs baseline: 1.5519x; 1.5519x over previous
//
#include <hip/hip_runtime.h>
#include <hip/hip_bf16.h>
#include <stdint.h>

typedef __attribute__((ext_vector_type(4))) float f32x4;
typedef __attribute__((ext_vector_type(8))) short short8;

#define NN 4096      // nodes
#define FIN 128
#define FHID 64
#define BATCH 32
#define NJ 2048      // BATCH * FHID

// ---------- helpers ----------
__device__ __forceinline__ unsigned short f2bf(float f) {
  unsigned u = __builtin_bit_cast(unsigned, f);
  u = (u + 0x7FFFu + ((u >> 16) & 1u)) >> 16;   // RNE
  return (unsigned short)u;
}
__device__ __forceinline__ float bf2f(unsigned short h) {
  unsigned u = ((unsigned)h) << 16;
  return __builtin_bit_cast(float, u);
}
__device__ __forceinline__ void gload_lds16(const void* g, void* l) {
  __builtin_amdgcn_global_load_lds(
      (const __attribute__((address_space(1))) unsigned int*)g,
      (__attribute__((address_space(3))) unsigned int*)l, 16, 0, 0);
}

// ---------- K0: adj fp32 -> bf16 ----------
__global__ __launch_bounds__(256) void k_convert(const float* __restrict__ adj,
                                                 unsigned short* __restrict__ adjb) {
  long i = (long)blockIdx.x * 256 + threadIdx.x;   // one float4 per thread
  const f32x4* in = (const f32x4*)adj;
  f32x4 v = in[i];
  ushort4 o;
  o.x = f2bf(v.x); o.y = f2bf(v.y); o.z = f2bf(v.z); o.w = f2bf(v.w);
  *(ushort4*)(adjb + i * 4) = o;
}

// ---------- K1: St[b*64+h][m] = sum_f x[b][m][f] * W1[f][h]  (bf16 out) ----------
// MFMA version: x cast to bf16 in regs, W1^T (bf16, padded) in LDS.
// Block = 256 thr (4 waves), handles 128 m-rows of one b. 1024 blocks.
__global__ __launch_bounds__(256) void k_support(const float* __restrict__ x,
                                                 const float* __restrict__ W1,
                                                 unsigned short* __restrict__ St) {
  __shared__ unsigned short W1t[FHID * 136];              // [h][f], pad 136
  __shared__ __align__(16) unsigned short T[FHID * 128];  // [h][m_loc]
  const int tid = threadIdx.x;
  // build W1^T bf16
  for (int i = tid; i < FIN * FHID; i += 256) {
    int f = i >> 6, h = i & 63;
    W1t[h * 136 + f] = f2bf(W1[i]);
  }
  __syncthreads();

  const int bb = blockIdx.x >> 5;            // b
  const int m0 = (blockIdx.x & 31) * 128;    // m block
  const int lane = tid & 63, wv = tid >> 6;
  const int fr = lane & 15, fq = lane >> 4;

  // B-frags: bfr[ni][ks] = W1t[ni*16+fr][ks*32 + fq*8 .. +8]
  short8 bfr[4][4];
  #pragma unroll
  for (int ni = 0; ni < 4; ++ni)
    #pragma unroll
    for (int ks = 0; ks < 4; ++ks)
      bfr[ni][ks] = *(const short8*)&W1t[(ni * 16 + fr) * 136 + ks * 32 + fq * 8];

  const float* xr0 = x + ((size_t)bb * NN + m0 + wv * 32 + fr) * FIN;
  const float* xr1 = xr0 + (size_t)16 * FIN;

  f32x4 z = {0.f, 0.f, 0.f, 0.f};
  f32x4 acc[2][4];
  #pragma unroll
  for (int mf = 0; mf < 2; ++mf)
    #pragma unroll
    for (int ni = 0; ni < 4; ++ni) acc[mf][ni] = z;

  #pragma unroll
  for (int ks = 0; ks < 4; ++ks) {
    #pragma unroll
    for (int mf = 0; mf < 2; ++mf) {
      const float* src = (mf ? xr1 : xr0) + ks * 32 + fq * 8;
      f32x4 lo = *(const f32x4*)src;
      f32x4 hi = *(const f32x4*)(src + 4);
      short8 a;
      #pragma unroll
      for (int j = 0; j < 4; ++j) { a[j] = (short)f2bf(lo[j]); a[4 + j] = (short)f2bf(hi[j]); }
      #pragma unroll
      for (int ni = 0; ni < 4; ++ni)
        acc[mf][ni] = __builtin_amdgcn_mfma_f32_16x16x32_bf16(a, bfr[ni][ks], acc[mf][ni], 0, 0, 0);
    }
  }

  // D layout: col(h) = lane&15, row(m) = (lane>>4)*4 + r
  const int cr = (lane >> 4) * 4, cc = lane & 15;
  #pragma unroll
  for (int mf = 0; mf < 2; ++mf)
    #pragma unroll
    for (int ni = 0; ni < 4; ++ni) {
      ushort4 o;
      o.x = f2bf(acc[mf][ni][0]); o.y = f2bf(acc[mf][ni][1]);
      o.z = f2bf(acc[mf][ni][2]); o.w = f2bf(acc[mf][ni][3]);
      *(ushort4*)&T[(ni * 16 + cc) * 128 + wv * 32 + mf * 16 + cr] = o;
    }
  __syncthreads();
  // coalesced 16B stores: 64 h-rows x 16 chunks
  for (int u = tid; u < FHID * 16; u += 256) {
    int row = u >> 4, ch = u & 15;
    *(short8*)(St + (size_t)(bb * FHID + row) * NN + m0 + ch * 8) =
        *(const short8*)&T[row * 128 + ch * 8];
  }
}

// ---------- K2: H = relu(adjb @ St^T + b1) ----------
// BM=256 x BN=128, BK=64, 8 waves (4M x 2N), dbuf LDS 96 KB.
// m201-style: per K-tile 2 phases of 16 MFMA; phase = {ds_reads; stages;
// barrier; setprio(1); MFMA x16; setprio(0); vmcnt(6); barrier}.
// Derived counted waits: vmcnt(6) steady, 6/2/0 tail. XOR-swizzle
// (byte ^= (row&7)<<4) via pre-swizzled global source, linear LDS dest.
#define VMW(N) asm volatile("s_waitcnt vmcnt(" #N ")" ::: "memory")

__global__ __launch_bounds__(512, 1) void k_gemm(const unsigned short* __restrict__ A,
                                                 const unsigned short* __restrict__ Bt,
                                                 const float* __restrict__ b1,
                                                 unsigned short* __restrict__ H) {
  __shared__ __align__(16) unsigned short As[2 * 16384];  // A: 256x64 dbuf, 64 KB
  __shared__ __align__(16) unsigned short Bs[2 * 8192];   // B: 128x64 dbuf, 32 KB

  const int tid  = threadIdx.x;
  const int lane = tid & 63;
  const int wv   = tid >> 6;
  const int wm   = wv >> 1;          // 0..3 (M)
  const int wn   = wv & 1;           // 0..1 (N)
  const int bm   = blockIdx.x * 256;
  const int bn   = blockIdx.y * 128;
  const int fr   = lane & 15;
  const int fq   = lane >> 4;

  // fragment LDS ushort offsets (buffer-relative)
  int offA[2][2][2], offB[4][2];
  #pragma unroll
  for (int h = 0; h < 2; ++h)
    #pragma unroll
    for (int m2 = 0; m2 < 2; ++m2) {
      int row = wm * 32 + h * 128 + m2 * 16 + fr;
      #pragma unroll
      for (int ks = 0; ks < 2; ++ks)
        offA[h][m2][ks] = row * 64 + ((((ks << 6) + (fq << 4)) ^ ((row & 7) << 4)) >> 1);
    }
  #pragma unroll
  for (int ni = 0; ni < 4; ++ni) {
    int row = wn * 32 + (ni & 1) * 16 + (ni >> 1) * 64 + fr;
    #pragma unroll
    for (int ks = 0; ks < 2; ++ks)
      offB[ni][ks] = row * 64 + ((((ks << 6) + (fq << 4)) ^ ((row & 7) << 4)) >> 1);
  }

  // staging addresses (pre-swizzled global source, linear LDS dest)
  const int srow = tid >> 3;
  const int scol = ((((tid & 7) << 4) ^ ((srow & 7) << 4)) >> 1);
  const unsigned short* gA00 = A + (size_t)(bm +   0 + srow) * NN + scol;
  const unsigned short* gA01 = A + (size_t)(bm +  64 + srow) * NN + scol;
  const unsigned short* gA10 = A + (size_t)(bm + 128 + srow) * NN + scol;
  const unsigned short* gA11 = A + (size_t)(bm + 192 + srow) * NN + scol;
  const unsigned short* gB0  = Bt + (size_t)(bn +  0 + srow) * NN + scol;
  const unsigned short* gB1  = Bt + (size_t)(bn + 64 + srow) * NN + scol;
  const int ld = tid * 8;

  f32x4 z = {0.f, 0.f, 0.f, 0.f};
  f32x4 acc[4][4];
  #pragma unroll
  for (int i = 0; i < 4; ++i)
    #pragma unroll
    for (int j = 0; j < 4; ++j) acc[i][j] = z;

  short8 av[2][2], bv[4][2];

#define STAGE_AH1(KO, BUF) {                                                   \
    gload_lds16(gA10 + (KO), As + (BUF) * 16384 + 2 * 4096 + ld);              \
    gload_lds16(gA11 + (KO), As + (BUF) * 16384 + 3 * 4096 + ld); }
#define STAGE_BAH0(KO, BUF) {                                                  \
    gload_lds16(gB0  + (KO), Bs + (BUF) * 8192  + 0 * 4096 + ld);              \
    gload_lds16(gB1  + (KO), Bs + (BUF) * 8192  + 1 * 4096 + ld);              \
    gload_lds16(gA00 + (KO), As + (BUF) * 16384 + 0 * 4096 + ld);              \
    gload_lds16(gA01 + (KO), As + (BUF) * 16384 + 1 * 4096 + ld); }
#define READS_P0(Ac, Bc)                                                       \
    _Pragma("unroll") for (int m2 = 0; m2 < 2; ++m2)                           \
    _Pragma("unroll") for (int ks = 0; ks < 2; ++ks)                           \
      av[m2][ks] = *(const short8*)((Ac) + offA[0][m2][ks]);                   \
    _Pragma("unroll") for (int ni = 0; ni < 4; ++ni)                           \
    _Pragma("unroll") for (int ks = 0; ks < 2; ++ks)                           \
      bv[ni][ks] = *(const short8*)((Bc) + offB[ni][ks]);
#define READS_P1(Ac)                                                           \
    _Pragma("unroll") for (int m2 = 0; m2 < 2; ++m2)                           \
    _Pragma("unroll") for (int ks = 0; ks < 2; ++ks)                           \
      av[m2][ks] = *(const short8*)((Ac) + offA[1][m2][ks]);
#define MFMA16(HH)                                                             \
    __builtin_amdgcn_s_setprio(1);                                             \
    _Pragma("unroll") for (int m2 = 0; m2 < 2; ++m2)                           \
    _Pragma("unroll") for (int ni = 0; ni < 4; ++ni)                           \
    _Pragma("unroll") for (int ks = 0; ks < 2; ++ks)                           \
      acc[2 * (HH) + m2][ni] = __builtin_amdgcn_mfma_f32_16x16x32_bf16(        \
          av[m2][ks], bv[ni][ks], acc[2 * (HH) + m2][ni], 0, 0, 0);            \
    __builtin_amdgcn_s_setprio(0);
#define BAR __builtin_amdgcn_s_barrier()

  // ---- prologue: B(0),A-h0(0)->buf0 [4]; A-h1(0)->buf0 [2]; B(1),A-h0(1)->buf1 [4]
  STAGE_BAH0(0, 0)
  STAGE_AH1(0, 0)
  STAGE_BAH0(64, 1)
  VMW(6);                 // B(0), A-h0(0) landed
  BAR;

  int kn1 = 64;           // k-col of tile t+1 (A-h1 stage)
  int kn2 = 128;          // k-col of tile t+2 (B, A-h0 stage)
  #pragma unroll 1
  for (int t = 0; t < 62; ++t) {
    const int cur = t & 1;
    const unsigned short* Ac = As + cur * 16384;
    const unsigned short* Bc = Bs + cur * 8192;
    // phase 0: C M-half 0
    READS_P0(Ac, Bc)
    STAGE_AH1(kn1, cur ^ 1)        // A-h1(t+1) -> other buf
    BAR;
    MFMA16(0)
    VMW(6);                         // A-h1(t) landed (for phase 1 reads)
    BAR;
    // phase 1: C M-half 1 (B held in regs)
    READS_P1(Ac)
    STAGE_BAH0(kn2, cur)           // B(t+2), A-h0(t+2) -> cur buf
    BAR;
    MFMA16(1)
    VMW(6);                         // B(t+1), A-h0(t+1) landed
    BAR;
    kn1 += 64; kn2 += 64;
  }
  // ---- t=62 (cur=0): stage only A-h1(63) ----
  {
    const unsigned short* Ac = As;
    const unsigned short* Bc = Bs;
    READS_P0(Ac, Bc)
    STAGE_AH1(63 * 64, 1)
    BAR;
    MFMA16(0)
    VMW(6);
    BAR;
    READS_P1(Ac)
    BAR;
    MFMA16(1)
    VMW(2);                         // B(63), A-h0(63) landed
    BAR;
  }
  // ---- t=63 (cur=1): no staging ----
  {
    const unsigned short* Ac = As + 16384;
    const unsigned short* Bc = Bs + 8192;
    READS_P0(Ac, Bc)
    BAR;
    MFMA16(0)
    VMW(0);                         // A-h1(63) landed
    BAR;
    READS_P1(Ac)
    MFMA16(1)
  }
#undef STAGE_AH1
#undef STAGE_BAH0
#undef READS_P0
#undef READS_P1
#undef MFMA16
#undef BAR

  // ---- epilogue: bias + relu, store bf16 ----
  const int cr = (lane >> 4) * 4;
  const int cc = lane & 15;
  #pragma unroll
  for (int ni = 0; ni < 4; ++ni) {
    int col = bn + wn * 32 + (ni & 1) * 16 + (ni >> 1) * 64 + cc;
    float bias = b1[col & 63];
    #pragma unroll
    for (int mi = 0; mi < 4; ++mi) {
      int rowb = bm + wm * 32 + (mi & 1) * 16 + (mi >> 1) * 128 + cr;
      #pragma unroll
      for (int r = 0; r < 4; ++r) {
        float v = acc[mi][ni][r] + bias;
        v = v > 0.f ? v : 0.f;
        H[(long)(rowb + r) * NJ + col] = f2bf(v);
      }
    }
  }
}

// ---------- K3: partial[b][c][h] = sum_{n in chunk c} adj[q_b][n] * H[n][b*64+h] ----------
__global__ __launch_bounds__(256) void k_agg(const float* __restrict__ adj,
                                             const int* __restrict__ q_ids,
                                             const unsigned short* __restrict__ H,
                                             float* __restrict__ partial) {
  int b = blockIdx.x;        // 0..31
  int c = blockIdx.y;        // 0..15
  int h = threadIdx.x & 63;
  int w = threadIdx.x >> 6;
  int q = q_ids[b];
  const float* arow = adj + (long)q * NN;
  int j = b * FHID + h;
  float s = 0.f;
  int n0 = c * 256;
  for (int n = n0 + w; n < n0 + 256; n += 4)
    s += arow[n] * bf2f(H[(long)n * NJ + j]);
  __shared__ float red[4][64];
  red[w][h] = s;
  __syncthreads();
  if (w == 0)
    partial[((b << 4) + c) * 64 + h] = red[0][h] + red[1][h] + red[2][h] + red[3][h];
}

// ---------- K4: out[b][l] = sum_h agg[b][h]*W2[h][l] + b2[l] ----------
__global__ __launch_bounds__(1024) void k_out(const float* __restrict__ partial,
                                              const float* __restrict__ W2,
                                              const float* __restrict__ b2,
                                              float* __restrict__ out) {
  __shared__ float aggs[BATCH * FHID];   // 2048
  int t = threadIdx.x;
  for (int idx = t; idx < BATCH * FHID; idx += 1024) {
    int base = (idx >> 6) * (16 * 64) + (idx & 63);
    float s = 0.f;
    #pragma unroll
    for (int c = 0; c < 16; ++c) s += partial[base + c * 64];
    aggs[idx] = s;
  }
  __syncthreads();
  int b = t >> 5, l = t & 31;
  float o = b2[l];
  #pragma unroll
  for (int h = 0; h < FHID; ++h) o += aggs[b * FHID + h] * W2[h * 32 + l];
  out[b * 32 + l] = o;
}

extern "C" void kernel_launch(void* const* d_in, const int* in_sizes, int n_in,
                              void* d_out, int out_size, void* d_ws, size_t ws_size,
                              hipStream_t stream) {
  const float* x   = (const float*)d_in[0];
  const int*   q   = (const int*)d_in[1];
  const float* adj = (const float*)d_in[2];
  const float* W1  = (const float*)d_in[3];
  const float* b1  = (const float*)d_in[4];
  const float* W2  = (const float*)d_in[5];
  const float* b2  = (const float*)d_in[6];
  float* out = (float*)d_out;

  char* ws = (char*)d_ws;
  unsigned short* adjb   = (unsigned short*)ws;                              // 32 MB
  unsigned short* St     = (unsigned short*)(ws + (size_t)32 * 1024 * 1024); // 16 MB
  unsigned short* H      = (unsigned short*)(ws + (size_t)48 * 1024 * 1024); // 16 MB
  float*          partial= (float*)(ws + (size_t)64 * 1024 * 1024);          // 128 KB

  // K0: adj -> bf16
  k_convert<<<(NN * NN / 4) / 256, 256, 0, stream>>>(adj, adjb);
  // K1: support^T via MFMA (1024 blocks x 256 thr)
  k_support<<<1024, 256, 0, stream>>>(x, W1, St);
  // K2: big GEMM + bias + relu (256x128 tiles, 2-phase/K-tile, vmcnt(6))
  dim3 g2(NN / 256, NJ / 128);
  k_gemm<<<g2, 512, 0, stream>>>(adjb, St, b1, H);
  // K3: row-gather aggregation
  dim3 g3(BATCH, 16);
  k_agg<<<g3, 256, 0, stream>>>(adj, q, H, partial);
  // K4: final tiny GEMM
  k_out<<<1, 1024, 0, stream>>>(partial, W2, b2, out);
}

// Round 6
// 124.118 us; speedup vs baseline: 1.6362x; 1.0543x over previous
//
#include <hip/hip_runtime.h>
#include <hip/hip_bf16.h>
#include <stdint.h>

typedef __attribute__((ext_vector_type(4))) float f32x4;
typedef __attribute__((ext_vector_type(8))) short short8;

#define NN 4096      // nodes
#define FIN 128
#define FHID 64
#define BATCH 32
#define NJ 2048      // BATCH * FHID

// ---------- helpers ----------
__device__ __forceinline__ unsigned short f2bf(float f) {
  unsigned u = __builtin_bit_cast(unsigned, f);
  u = (u + 0x7FFFu + ((u >> 16) & 1u)) >> 16;   // RNE
  return (unsigned short)u;
}
__device__ __forceinline__ float bf2f(unsigned short h) {
  unsigned u = ((unsigned)h) << 16;
  return __builtin_bit_cast(float, u);
}
__device__ __forceinline__ void gload_lds16(const void* g, void* l) {
  __builtin_amdgcn_global_load_lds(
      (const __attribute__((address_space(1))) unsigned int*)g,
      (__attribute__((address_space(3))) unsigned int*)l, 16, 0, 0);
}

// ---------- K0: adj fp32 -> bf16 ----------
__global__ __launch_bounds__(256) void k_convert(const float* __restrict__ adj,
                                                 unsigned short* __restrict__ adjb) {
  long i = (long)blockIdx.x * 256 + threadIdx.x;   // one float4 per thread
  const f32x4* in = (const f32x4*)adj;
  f32x4 v = in[i];
  ushort4 o;
  o.x = f2bf(v.x); o.y = f2bf(v.y); o.z = f2bf(v.z); o.w = f2bf(v.w);
  *(ushort4*)(adjb + i * 4) = o;
}

// ---------- K1: St[b*64+h][m] = sum_f x[b][m][f] * W1[f][h]  (bf16 out) ----------
// MFMA version: x cast to bf16 in regs, W1^T (bf16, padded) in LDS.
__global__ __launch_bounds__(256) void k_support(const float* __restrict__ x,
                                                 const float* __restrict__ W1,
                                                 unsigned short* __restrict__ St) {
  __shared__ unsigned short W1t[FHID * 136];              // [h][f], pad 136
  __shared__ __align__(16) unsigned short T[FHID * 128];  // [h][m_loc]
  const int tid = threadIdx.x;
  for (int i = tid; i < FIN * FHID; i += 256) {
    int f = i >> 6, h = i & 63;
    W1t[h * 136 + f] = f2bf(W1[i]);
  }
  __syncthreads();

  const int bb = blockIdx.x >> 5;            // b
  const int m0 = (blockIdx.x & 31) * 128;    // m block
  const int lane = tid & 63, wv = tid >> 6;
  const int fr = lane & 15, fq = lane >> 4;

  short8 bfr[4][4];
  #pragma unroll
  for (int ni = 0; ni < 4; ++ni)
    #pragma unroll
    for (int ks = 0; ks < 4; ++ks)
      bfr[ni][ks] = *(const short8*)&W1t[(ni * 16 + fr) * 136 + ks * 32 + fq * 8];

  const float* xr0 = x + ((size_t)bb * NN + m0 + wv * 32 + fr) * FIN;
  const float* xr1 = xr0 + (size_t)16 * FIN;

  f32x4 z = {0.f, 0.f, 0.f, 0.f};
  f32x4 acc[2][4];
  #pragma unroll
  for (int mf = 0; mf < 2; ++mf)
    #pragma unroll
    for (int ni = 0; ni < 4; ++ni) acc[mf][ni] = z;

  #pragma unroll
  for (int ks = 0; ks < 4; ++ks) {
    #pragma unroll
    for (int mf = 0; mf < 2; ++mf) {
      const float* src = (mf ? xr1 : xr0) + ks * 32 + fq * 8;
      f32x4 lo = *(const f32x4*)src;
      f32x4 hi = *(const f32x4*)(src + 4);
      short8 a;
      #pragma unroll
      for (int j = 0; j < 4; ++j) { a[j] = (short)f2bf(lo[j]); a[4 + j] = (short)f2bf(hi[j]); }
      #pragma unroll
      for (int ni = 0; ni < 4; ++ni)
        acc[mf][ni] = __builtin_amdgcn_mfma_f32_16x16x32_bf16(a, bfr[ni][ks], acc[mf][ni], 0, 0, 0);
    }
  }

  const int cr = (lane >> 4) * 4, cc = lane & 15;
  #pragma unroll
  for (int mf = 0; mf < 2; ++mf)
    #pragma unroll
    for (int ni = 0; ni < 4; ++ni) {
      ushort4 o;
      o.x = f2bf(acc[mf][ni][0]); o.y = f2bf(acc[mf][ni][1]);
      o.z = f2bf(acc[mf][ni][2]); o.w = f2bf(acc[mf][ni][3]);
      *(ushort4*)&T[(ni * 16 + cc) * 128 + wv * 32 + mf * 16 + cr] = o;
    }
  __syncthreads();
  for (int u = tid; u < FHID * 16; u += 256) {
    int row = u >> 4, ch = u & 15;
    *(short8*)(St + (size_t)(bb * FHID + row) * NN + m0 + ch * 8) =
        *(const short8*)&T[row * 128 + ch * 8];
  }
}

// ---------- K2: H = relu(adjb @ St^T + b1) ----------
// BM=256 x BN=128, BK=64, 8 waves (4M x 2N), per-wave 64x64, dbuf LDS 96 KB.
// 4 balanced phases per K-tile (snake quadrant order), each:
// {4 ds_read_b128; 0-3 stage issues; barrier; lgkmcnt(0); setprio; 8 MFMA}.
// bvA(np0) for tile t+1 is read in P3 of tile t AFTER vmcnt(3)+barrier
// (per-wave vmcnt + barrier = all-waves staged data visible), reg dbuf.
// One vmcnt per tile. XOR-swizzle via pre-swizzled global source.
#define VMW(N)  asm volatile("s_waitcnt vmcnt(" #N ")" ::: "memory")
#define LGKM0   asm volatile("s_waitcnt lgkmcnt(0)" ::: "memory")
#define BAR     __builtin_amdgcn_s_barrier()

__global__ __launch_bounds__(512, 1) void k_gemm(const unsigned short* __restrict__ A,
                                                 const unsigned short* __restrict__ Bt,
                                                 const float* __restrict__ b1,
                                                 unsigned short* __restrict__ H) {
  __shared__ __align__(16) unsigned short As[2 * 16384];  // A: 256x64 dbuf, 64 KB
  __shared__ __align__(16) unsigned short Bs[2 * 8192];   // B: 128x64 dbuf, 32 KB

  const int tid  = threadIdx.x;
  const int lane = tid & 63;
  const int wv   = tid >> 6;
  const int wm   = wv >> 1;          // 0..3 (M)
  const int wn   = wv & 1;           // 0..1 (N)
  const int bm   = blockIdx.x * 256;
  const int bn   = blockIdx.y * 128;
  const int fr   = lane & 15;
  const int fq   = lane >> 4;

  // fragment LDS ushort offsets (buffer-relative)
  int offA[2][2][2], offB[4][2];
  #pragma unroll
  for (int h = 0; h < 2; ++h)
    #pragma unroll
    for (int m2 = 0; m2 < 2; ++m2) {
      int row = wm * 32 + h * 128 + m2 * 16 + fr;
      #pragma unroll
      for (int ks = 0; ks < 2; ++ks)
        offA[h][m2][ks] = row * 64 + ((((ks << 6) + (fq << 4)) ^ ((row & 7) << 4)) >> 1);
    }
  #pragma unroll
  for (int ni = 0; ni < 4; ++ni) {
    int row = wn * 32 + (ni & 1) * 16 + (ni >> 1) * 64 + fr;
    #pragma unroll
    for (int ks = 0; ks < 2; ++ks)
      offB[ni][ks] = row * 64 + ((((ks << 6) + (fq << 4)) ^ ((row & 7) << 4)) >> 1);
  }

  // staging addresses (pre-swizzled global source, linear LDS dest)
  const int srow = tid >> 3;
  const int scol = ((((tid & 7) << 4) ^ ((srow & 7) << 4)) >> 1);
  const unsigned short* gA00 = A + (size_t)(bm +   0 + srow) * NN + scol;
  const unsigned short* gA01 = A + (size_t)(bm +  64 + srow) * NN + scol;
  const unsigned short* gA10 = A + (size_t)(bm + 128 + srow) * NN + scol;
  const unsigned short* gA11 = A + (size_t)(bm + 192 + srow) * NN + scol;
  const unsigned short* gB0  = Bt + (size_t)(bn +  0 + srow) * NN + scol;
  const unsigned short* gB1  = Bt + (size_t)(bn + 64 + srow) * NN + scol;
  const int ld = tid * 8;

  f32x4 z = {0.f, 0.f, 0.f, 0.f};
  f32x4 acc[4][4];
  #pragma unroll
  for (int i = 0; i < 4; ++i)
    #pragma unroll
    for (int j = 0; j < 4; ++j) acc[i][j] = z;

  short8 av0[2][2], av1[2][2], bvB[2][2], bvA0[2][2], bvA1[2][2];

#define RD_AVA(Ac)                                                             \
    _Pragma("unroll") for (int m2 = 0; m2 < 2; ++m2)                           \
    _Pragma("unroll") for (int ks = 0; ks < 2; ++ks)                           \
      av0[m2][ks] = *(const short8*)((Ac) + offA[0][m2][ks]);
#define RD_AVB(Ac)                                                             \
    _Pragma("unroll") for (int m2 = 0; m2 < 2; ++m2)                           \
    _Pragma("unroll") for (int ks = 0; ks < 2; ++ks)                           \
      av1[m2][ks] = *(const short8*)((Ac) + offA[1][m2][ks]);
#define RD_BV(DST, Bb, P)                                                      \
    _Pragma("unroll") for (int n2 = 0; n2 < 2; ++n2)                           \
    _Pragma("unroll") for (int ks = 0; ks < 2; ++ks)                           \
      DST[n2][ks] = *(const short8*)((Bb) + offB[2 * (P) + n2][ks]);
#define MFMA8(MP, AV, BV, NP)                                                  \
    __builtin_amdgcn_s_setprio(1);                                             \
    _Pragma("unroll") for (int m2 = 0; m2 < 2; ++m2)                           \
    _Pragma("unroll") for (int n2 = 0; n2 < 2; ++n2)                           \
    _Pragma("unroll") for (int ks = 0; ks < 2; ++ks)                           \
      acc[2 * (MP) + m2][2 * (NP) + n2] = __builtin_amdgcn_mfma_f32_16x16x32_bf16( \
          AV[m2][ks], BV[n2][ks], acc[2 * (MP) + m2][2 * (NP) + n2], 0, 0, 0); \
    __builtin_amdgcn_s_setprio(0);

// One K-tile, 4 phases. CUR = buffer index; BVA_C = bvA regs for this tile;
// BVA_N = bvA regs to fill for next tile; KQ = k-elem offset staged (tile t+2).
// DOS: 1 = do staging. VMN: vmcnt count at P3.
#define TILE(CUR, BVA_C, BVA_N, KQ, DOS, VMWOP) {                              \
    const unsigned short* Ac = As + (CUR) * 16384;                             \
    const unsigned short* Bc = Bs + (CUR) * 8192;                              \
    const unsigned short* Bn = Bs + (1 - (CUR)) * 8192;                        \
    /* P0: Q(0,0) */                                                           \
    RD_AVA(Ac)                                                                 \
    BAR; LGKM0;                                                                \
    MFMA8(0, av0, BVA_C, 0)                                                    \
    /* P1: Q(0,1); stage A-h0(t+2) */                                          \
    RD_BV(bvB, Bc, 1)                                                          \
    if (DOS) {                                                                 \
      gload_lds16(gA00 + (KQ), As + (CUR) * 16384 + 0 * 4096 + ld);            \
      gload_lds16(gA01 + (KQ), As + (CUR) * 16384 + 1 * 4096 + ld);            \
    }                                                                          \
    BAR; LGKM0;                                                                \
    MFMA8(0, av0, bvB, 1)                                                      \
    /* P2: Q(1,1); stage B-h1(t+2) */                                          \
    RD_AVB(Ac)                                                                 \
    if (DOS) {                                                                 \
      gload_lds16(gB1 + (KQ), Bs + (CUR) * 8192 + 1 * 4096 + ld);              \
    }                                                                          \
    BAR; LGKM0;                                                                \
    MFMA8(1, av1, bvB, 1)                                                      \
    /* P3: Q(1,0); vmcnt; stage A-h1,B-h0(t+2); read bvA(t+1) post-barrier */  \
    VMWOP;                                                                     \
    if (DOS) {                                                                 \
      gload_lds16(gA10 + (KQ), As + (CUR) * 16384 + 2 * 4096 + ld);            \
      gload_lds16(gA11 + (KQ), As + (CUR) * 16384 + 3 * 4096 + ld);            \
      gload_lds16(gB0  + (KQ), Bs + (CUR) * 8192 + 0 * 4096 + ld);             \
    }                                                                          \
    BAR;                                                                       \
    RD_BV(BVA_N, Bn, 0)                                                        \
    MFMA8(1, av1, BVA_C, 0)                                                    \
  }

  // ---- prologue: stage tile0 -> buf0, tile1 -> buf1 ----
  gload_lds16(gB0,       Bs + 0 * 4096 + ld);
  gload_lds16(gB1,       Bs + 1 * 4096 + ld);
  gload_lds16(gA00,      As + 0 * 4096 + ld);
  gload_lds16(gA01,      As + 1 * 4096 + ld);
  gload_lds16(gA10,      As + 2 * 4096 + ld);
  gload_lds16(gA11,      As + 3 * 4096 + ld);
  gload_lds16(gB0  + 64, Bs + 8192 + 0 * 4096 + ld);
  gload_lds16(gB1  + 64, Bs + 8192 + 1 * 4096 + ld);
  gload_lds16(gA00 + 64, As + 16384 + 0 * 4096 + ld);
  gload_lds16(gA01 + 64, As + 16384 + 1 * 4096 + ld);
  gload_lds16(gA10 + 64, As + 16384 + 2 * 4096 + ld);
  gload_lds16(gA11 + 64, As + 16384 + 3 * 4096 + ld);
  VMW(6);                 // own tile-0 loads drained
  BAR;                    // => all waves' tile-0 loads visible
  RD_BV(bvA0, Bs, 0)      // prime bvA for tile 0 (waited at tile0 P0 LGKM0)

  // ---- main loop: 31 macro-iters = tiles 0..61 ----
  int kq = 128;           // k-elem offset of tile t+2
  #pragma unroll 1
  for (int g = 0; g < 31; ++g) {
    TILE(0, bvA0, bvA1, kq,      1, VMW(3))
    TILE(1, bvA1, bvA0, kq + 64, 1, VMW(3))
    kq += 128;
  }
  // ---- tile 62 (buf0): no staging; drain for tile 63 ----
  TILE(0, bvA0, bvA1, 0, 0, VMW(0))
  // ---- tile 63 (buf1): last, no bvA-next / no vmcnt ----
  {
    const unsigned short* Ac = As + 16384;
    const unsigned short* Bc = Bs + 8192;
    RD_AVA(Ac)
    BAR; LGKM0;
    MFMA8(0, av0, bvA1, 0)
    RD_BV(bvB, Bc, 1)
    BAR; LGKM0;
    MFMA8(0, av0, bvB, 1)
    RD_AVB(Ac)
    BAR; LGKM0;
    MFMA8(1, av1, bvB, 1)
    MFMA8(1, av1, bvA1, 0)
  }
#undef RD_AVA
#undef RD_AVB
#undef RD_BV
#undef MFMA8
#undef TILE

  // ---- epilogue: bias + relu, store bf16 ----
  const int cr = (lane >> 4) * 4;
  const int cc = lane & 15;
  #pragma unroll
  for (int ni = 0; ni < 4; ++ni) {
    int col = bn + wn * 32 + (ni & 1) * 16 + (ni >> 1) * 64 + cc;
    float bias = b1[col & 63];
    #pragma unroll
    for (int mi = 0; mi < 4; ++mi) {
      int rowb = bm + wm * 32 + (mi & 1) * 16 + (mi >> 1) * 128 + cr;
      #pragma unroll
      for (int r = 0; r < 4; ++r) {
        float v = acc[mi][ni][r] + bias;
        v = v > 0.f ? v : 0.f;
        H[(long)(rowb + r) * NJ + col] = f2bf(v);
      }
    }
  }
}

// ---------- K3: partial[b][c][h] = sum_{n in chunk c} adj[q_b][n] * H[n][b*64+h] ----------
__global__ __launch_bounds__(256) void k_agg(const float* __restrict__ adj,
                                             const int* __restrict__ q_ids,
                                             const unsigned short* __restrict__ H,
                                             float* __restrict__ partial) {
  int b = blockIdx.x;        // 0..31
  int c = blockIdx.y;        // 0..15
  int h = threadIdx.x & 63;
  int w = threadIdx.x >> 6;
  int q = q_ids[b];
  const float* arow = adj + (long)q * NN;
  int j = b * FHID + h;
  float s = 0.f;
  int n0 = c * 256;
  for (int n = n0 + w; n < n0 + 256; n += 4)
    s += arow[n] * bf2f(H[(long)n * NJ + j]);
  __shared__ float red[4][64];
  red[w][h] = s;
  __syncthreads();
  if (w == 0)
    partial[((b << 4) + c) * 64 + h] = red[0][h] + red[1][h] + red[2][h] + red[3][h];
}

// ---------- K4: out[b][l] = sum_h agg[b][h]*W2[h][l] + b2[l] ----------
__global__ __launch_bounds__(1024) void k_out(const float* __restrict__ partial,
                                              const float* __restrict__ W2,
                                              const float* __restrict__ b2,
                                              float* __restrict__ out) {
  __shared__ float aggs[BATCH * FHID];   // 2048
  int t = threadIdx.x;
  for (int idx = t; idx < BATCH * FHID; idx += 1024) {
    int base = (idx >> 6) * (16 * 64) + (idx & 63);
    float s = 0.f;
    #pragma unroll
    for (int c = 0; c < 16; ++c) s += partial[base + c * 64];
    aggs[idx] = s;
  }
  __syncthreads();
  int b = t >> 5, l = t & 31;
  float o = b2[l];
  #pragma unroll
  for (int h = 0; h < FHID; ++h) o += aggs[b * FHID + h] * W2[h * 32 + l];
  out[b * 32 + l] = o;
}

extern "C" void kernel_launch(void* const* d_in, const int* in_sizes, int n_in,
                              void* d_out, int out_size, void* d_ws, size_t ws_size,
                              hipStream_t stream) {
  const float* x   = (const float*)d_in[0];
  const int*   q   = (const int*)d_in[1];
  const float* adj = (const float*)d_in[2];
  const float* W1  = (const float*)d_in[3];
  const float* b1  = (const float*)d_in[4];
  const float* W2  = (const float*)d_in[5];
  const float* b2  = (const float*)d_in[6];
  float* out = (float*)d_out;

  char* ws = (char*)d_ws;
  unsigned short* adjb   = (unsigned short*)ws;                              // 32 MB
  unsigned short* St     = (unsigned short*)(ws + (size_t)32 * 1024 * 1024); // 16 MB
  unsigned short* H      = (unsigned short*)(ws + (size_t)48 * 1024 * 1024); // 16 MB
  float*          partial= (float*)(ws + (size_t)64 * 1024 * 1024);          // 128 KB

  // K0: adj -> bf16
  k_convert<<<(NN * NN / 4) / 256, 256, 0, stream>>>(adj, adjb);
  // K1: support^T via MFMA
  k_support<<<1024, 256, 0, stream>>>(x, W1, St);
  // K2: big GEMM + bias + relu (256x128 tiles, 4 balanced phases/K-tile)
  dim3 g2(NN / 256, NJ / 128);
  k_gemm<<<g2, 512, 0, stream>>>(adjb, St, b1, H);
  // K3: row-gather aggregation
  dim3 g3(BATCH, 16);
  k_agg<<<g3, 256, 0, stream>>>(adj, q, H, partial);
  // K4: final tiny GEMM
  k_out<<<1, 1024, 0, stream>>>(partial, W2, b2, out);
}